// Round 14
// baseline (255.034 us; speedup 1.0000x reference)
//
#include <hip/hip_runtime.h>
#include <math.h>

#define N_NODES 10000
#define N_EDGES 160000
#define FDIM    512
#define DOUT    256
#define NCAT    768     // [W0-W2 | W1 | W2]

typedef unsigned short ushort_t;
typedef unsigned int   uint_t;
typedef __attribute__((ext_vector_type(8))) short bf16x8;
typedef __attribute__((ext_vector_type(4))) float f32x4;

// ---------------------------------------------------------------------------
// helpers
// ---------------------------------------------------------------------------
__device__ inline ushort_t f2bf(float f) {
    uint_t u = __float_as_uint(f);
    u += 0x7fffu + ((u >> 16) & 1u);        // round-to-nearest-even
    return (ushort_t)(u >> 16);
}
__device__ inline void bf2f8(uint4 u, float* v) {
    v[0] = __uint_as_float(u.x << 16); v[1] = __uint_as_float(u.x & 0xffff0000u);
    v[2] = __uint_as_float(u.y << 16); v[3] = __uint_as_float(u.y & 0xffff0000u);
    v[4] = __uint_as_float(u.z << 16); v[5] = __uint_as_float(u.z & 0xffff0000u);
    v[6] = __uint_as_float(u.w << 16); v[7] = __uint_as_float(u.w & 0xffff0000u);
}
__device__ inline uint4 f2bf8v(const float* v) {
    uint4 u;
    u.x = (uint_t)f2bf(v[0]) | ((uint_t)f2bf(v[1]) << 16);
    u.y = (uint_t)f2bf(v[2]) | ((uint_t)f2bf(v[3]) << 16);
    u.z = (uint_t)f2bf(v[4]) | ((uint_t)f2bf(v[5]) << 16);
    u.w = (uint_t)f2bf(v[6]) | ((uint_t)f2bf(v[7]) << 16);
    return u;
}
__device__ inline void gld_lds16(const ushort_t* g, ushort_t* l) {
    __builtin_amdgcn_global_load_lds(
        (const __attribute__((address_space(1))) unsigned int*)g,
        (__attribute__((address_space(3))) unsigned int*)l,
        16, 0, 0);
}

// ---------------------------------------------------------------------------
// Merged preprocessing: edge degrees (atomics) + weight transposes.
// (xb conversion REMOVED — layer 1 now aggregates the fp32 input directly:
//  Â(xW) = (Âx)W, so x never needs a standalone bf16 copy.)
// ---------------------------------------------------------------------------
#define EDGE_BLOCKS 625   // 160000 / 256

__global__ __launch_bounds__(256) void k_pre1(
    const int* __restrict__ row, const int* __restrict__ col,
    const float* __restrict__ w,
    float* deg_g, float* deg_c, int* counts,
    const float* __restrict__ W1, ushort_t* __restrict__ W1t,
    const float* __restrict__ W2, ushort_t* __restrict__ W2t,
    const float* __restrict__ Wc, ushort_t* __restrict__ Wcatt)
{
    __shared__ float tile[64][65];
    int b = blockIdx.x;
    int tid = threadIdx.x;
    if (b < EDGE_BLOCKS) {
        int e = b * 256 + tid;
        if (e < N_EDGES) {
            int r = row[e], c = col[e];
            float wv = w[e];
            atomicAdd(&deg_g[c], wv);
            if (r != c) atomicAdd(&deg_c[r], wv);
            atomicAdd(&counts[c], 1);
        }
        return;
    }
    b -= EDGE_BLOCKS;
    const float* src; const float* src2 = nullptr;
    ushort_t* dst; int kt, ntG, srcld;
    if (b < 64) {                       // W1 [512][512]
        kt = b >> 3; ntG = b & 7; srcld = FDIM;
        src = W1 + (size_t)(kt * 64) * FDIM + ntG * 64;
        dst = W1t;
    } else if (b < 128) {               // W2
        int bb = b - 64;
        kt = bb >> 3; ntG = bb & 7; srcld = FDIM;
        src = W2 + (size_t)(kt * 64) * FDIM + ntG * 64;
        dst = W2t;
    } else {                            // Wcat: ntG in [0,12), kt in [0,8)
        int bb = b - 128;
        ntG = bb / 8; kt = bb % 8; srcld = DOUT;
        int s = ntG >> 2;               // section 0,1,2
        int nl = (ntG & 3) * 64;        // col within 256
        if (s == 0) {                   // W0 - W2
            src  = Wc + (size_t)(kt * 64) * DOUT + nl;
            src2 = Wc + (size_t)2 * FDIM * DOUT + (size_t)(kt * 64) * DOUT + nl;
        } else if (s == 1) {            // W1 (Cheb k=1)
            src  = Wc + (size_t)1 * FDIM * DOUT + (size_t)(kt * 64) * DOUT + nl;
        } else {                        // W2
            src  = Wc + (size_t)2 * FDIM * DOUT + (size_t)(kt * 64) * DOUT + nl;
        }
        dst = Wcatt;
    }
    // load phase: thread (r = tid>>2, c0 = (tid&3)*16) loads 16 floats
    {
        int r = tid >> 2, c0 = (tid & 3) * 16;
        const float* sp = src + (size_t)r * srcld + c0;
#pragma unroll
        for (int q = 0; q < 4; ++q) {
            float4 a = *(const float4*)(sp + q * 4);
            if (src2) {
                float4 bsub = *(const float4*)(src2 + (size_t)r * srcld + c0 + q * 4);
                a.x -= bsub.x; a.y -= bsub.y; a.z -= bsub.z; a.w -= bsub.w;
            }
            tile[r][c0 + q * 4 + 0] = a.x;
            tile[r][c0 + q * 4 + 1] = a.y;
            tile[r][c0 + q * 4 + 2] = a.z;
            tile[r][c0 + q * 4 + 3] = a.w;
        }
    }
    __syncthreads();
    // store phase: thread (n = tid>>2, k0 = (tid&3)*16) writes 16 bf16 (32 B)
    {
        int n = tid >> 2, k0 = (tid & 3) * 16;
        float v[16];
#pragma unroll
        for (int i = 0; i < 16; ++i) v[i] = tile[k0 + i][n];
        uint4 u0 = f2bf8v(v);
        uint4 u1 = f2bf8v(v + 8);
        ushort_t* dp = dst + (size_t)(ntG * 64 + n) * FDIM + kt * 64 + k0;
        *(uint4*)dp = u0;
        *(uint4*)(dp + 8) = u1;
    }
}

__global__ __launch_bounds__(256) void k_dinv_scan1(
    const float* __restrict__ deg_g, const float* __restrict__ deg_c,
    float* __restrict__ dinv_g, float* __restrict__ dinv_c,
    const int* __restrict__ counts, int* __restrict__ rp,
    int* __restrict__ part, int n)
{
    __shared__ int s[256];
    int tid = threadIdx.x;
    int i = blockIdx.x * 256 + tid;
    if (i < n) {
        dinv_g[i] = rsqrtf(deg_g[i] + 1.0f);
        float d = deg_c[i];
        dinv_c[i] = d > 0.f ? rsqrtf(d) : 0.f;
    }
    int v = (i < n) ? counts[i] : 0;
    s[tid] = v;
    __syncthreads();
    for (int o = 1; o < 256; o <<= 1) {
        int t = (tid >= o) ? s[tid - o] : 0;
        __syncthreads();
        s[tid] += t;
        __syncthreads();
    }
    if (i < n) rp[i] = s[tid] - v;
    if (tid == 255) part[blockIdx.x] = s[255];
}

// fused scan2+scan3: every block redundantly wave-scans the <=64 partials
__global__ __launch_bounds__(256) void k_scan23(int* __restrict__ rp,
                                                const int* __restrict__ part,
                                                int nb, int n) {
    __shared__ int soff[64];
    __shared__ int stot;
    int tid = threadIdx.x;
    if (tid < 64) {
        int v = (tid < nb) ? part[tid] : 0;
        int x = v;
        for (int o = 1; o < 64; o <<= 1) {
            int y = __shfl_up(x, o, 64);
            if (tid >= o) x += y;
        }
        soff[tid] = x - v;
        if (tid == 63) stot = x;
    }
    __syncthreads();
    int i = blockIdx.x * 256 + tid;
    if (i < n) rp[i] += soff[blockIdx.x];
    if (blockIdx.x == 0 && tid == 0) rp[n] = stot;
}

// edge records (src, norm) 8B; n_c stored NEGATED so lhat is a plain sum
__global__ void k_fill(const int* __restrict__ row, const int* __restrict__ col,
                       const float* __restrict__ w,
                       const float* __restrict__ dinv_g, const float* __restrict__ dinv_c,
                       const int* __restrict__ rp, int* __restrict__ fill,
                       int2* __restrict__ eg, int2* __restrict__ ec, int E) {
    int e = blockIdx.x * blockDim.x + threadIdx.x;
    if (e >= E) return;
    int r = row[e], c = col[e];
    float wv = w[e];
    float ng = dinv_g[r] * wv * dinv_g[c];
    float w0 = (r == c) ? 0.f : wv;
    float nc = -(dinv_c[r] * w0 * dinv_c[c]);
    int pos = rp[c] + atomicAdd(&fill[c], 1);
    eg[pos] = make_int2(r, __float_as_int(ng));
    ec[pos] = make_int2(r, __float_as_int(nc));
}

// ---------------------------------------------------------------------------
// Staged bf16 MFMA GEMM (m97 structure). 64x128 tile, BK=32, 256 thr =
// 4 waves 2x2; wave tile 32x64 -> 2x4 MFMA 16x16x32. 12 KB LDS.
// Optional epilogue: +bias then celu (fp32 domain) before bf16 store.
// XCD swizzle: j=id&7 -> XCD; bx=(t/nby)*8+j.
// ---------------------------------------------------------------------------
__global__ __launch_bounds__(256) void k_mgemm(
    const ushort_t* __restrict__ A, int lda,
    const ushort_t* __restrict__ Bt, int ldb,
    int M, int K, int N, int nbx, int nby,
    const float* __restrict__ bias,
    ushort_t* __restrict__ outB)
{
    __shared__ ushort_t As[64 * 32];
    __shared__ ushort_t Bs[128 * 32];

    int id = blockIdx.x;
    int j = id & 7, t = id >> 3;
    int by = t % nby;
    int bx = (t / nby) * 8 + j;
    if (bx >= nbx) return;

    const int tid  = threadIdx.x;
    const int w    = tid >> 6;
    const int lane = tid & 63;
    const int l15  = lane & 15;
    const int quad = lane >> 4;
    const int bm = bx * 64, bn = by * 128;
    const int wm = (w & 1) * 32;
    const int wn = (w >> 1) * 64;

    const int sr = lane >> 2;           // 0..15
    const int sc = (lane & 3) * 8;      // 0,8,16,24
    int arow = min(bm + w * 16 + sr, M - 1);
    const ushort_t* ag = A + (size_t)arow * lda + sc;
    ushort_t* al = As + (w * 16 + sr) * 32 + sc;
    const ushort_t* bg0 = Bt + (size_t)(bn + w * 32 + sr) * ldb + sc;
    const ushort_t* bg1 = bg0 + (size_t)16 * ldb;
    ushort_t* bl0 = Bs + (w * 32 + sr) * 32 + sc;
    ushort_t* bl1 = bl0 + 16 * 32;

    f32x4 acc[2][4] = {};

    for (int k0 = 0; k0 < K; k0 += 32) {
        __syncthreads();
        gld_lds16(ag + k0, al);
        gld_lds16(bg0 + k0, bl0);
        gld_lds16(bg1 + k0, bl1);
        __syncthreads();
        bf16x8 af[2], bfr[4];
#pragma unroll
        for (int i = 0; i < 2; ++i)
            af[i] = *(const bf16x8*)(As + (wm + i * 16 + l15) * 32 + quad * 8);
#pragma unroll
        for (int jj = 0; jj < 4; ++jj)
            bfr[jj] = *(const bf16x8*)(Bs + (wn + jj * 16 + l15) * 32 + quad * 8);
#pragma unroll
        for (int i = 0; i < 2; ++i)
#pragma unroll
            for (int jj = 0; jj < 4; ++jj)
                acc[i][jj] = __builtin_amdgcn_mfma_f32_16x16x32_bf16(af[i], bfr[jj], acc[i][jj], 0, 0, 0);
    }

    // C/D layout: col = lane&15, row = quad*4 + reg (m89-verified)
#pragma unroll
    for (int i = 0; i < 2; ++i) {
        int rowb = bm + wm + i * 16 + quad * 4;
#pragma unroll
        for (int jj = 0; jj < 4; ++jj) {
            int col = bn + wn + jj * 16 + l15;
#pragma unroll
            for (int r = 0; r < 4; ++r) {
                int rr = rowb + r;
                if (rr < M) {
                    float v = acc[i][jj][r];
                    if (bias) {
                        v += bias[col];
                        v = v > 0.f ? v : expm1f(v);
                    }
                    outB[(size_t)rr * N + col] = f2bf(v);
                }
            }
        }
    }
}

// ---------------------------------------------------------------------------
// XCD-feature-sliced aggregation over fp32 input (layer 1: Z = Âx, bf16 out).
// 8 slices of 64 features. Block 256 thr = 32 consecutive nodes x 8 lanes.
// Per-XCD gather set = 10000*256B = 2.56 MB -> fits private 4 MB L2.
// ---------------------------------------------------------------------------
__global__ __launch_bounds__(256) void k_saggF(
    const float* __restrict__ h,
    const int2* __restrict__ er, const int* __restrict__ rp,
    const float* __restrict__ dinv_g,
    ushort_t* __restrict__ outB)
{
    const int id  = blockIdx.x;
    const int sl  = id & 7;
    const int tid = threadIdx.x;
    const int c   = (id >> 3) * 32 + (tid >> 3);
    if (c >= N_NODES) return;
    const int f = sl * 64 + ((tid & 7) << 3);
    const float* hp = h + f;

    float acc[8] = {0.f, 0.f, 0.f, 0.f, 0.f, 0.f, 0.f, 0.f};
    int e = rp[c];
    const int e1 = rp[c + 1];
    for (; e + 2 <= e1; e += 2) {
        int2 p0 = er[e], p1 = er[e + 1];
        const float* s0 = hp + (size_t)p0.x * FDIM;
        const float* s1 = hp + (size_t)p1.x * FDIM;
        float4 a0 = *(const float4*)s0, b0 = *(const float4*)(s0 + 4);
        float4 a1 = *(const float4*)s1, b1v = *(const float4*)(s1 + 4);
        float n0 = __int_as_float(p0.y), n1 = __int_as_float(p1.y);
        acc[0] = fmaf(n0, a0.x, acc[0]); acc[1] = fmaf(n0, a0.y, acc[1]);
        acc[2] = fmaf(n0, a0.z, acc[2]); acc[3] = fmaf(n0, a0.w, acc[3]);
        acc[4] = fmaf(n0, b0.x, acc[4]); acc[5] = fmaf(n0, b0.y, acc[5]);
        acc[6] = fmaf(n0, b0.z, acc[6]); acc[7] = fmaf(n0, b0.w, acc[7]);
        acc[0] = fmaf(n1, a1.x, acc[0]); acc[1] = fmaf(n1, a1.y, acc[1]);
        acc[2] = fmaf(n1, a1.z, acc[2]); acc[3] = fmaf(n1, a1.w, acc[3]);
        acc[4] = fmaf(n1, b1v.x, acc[4]); acc[5] = fmaf(n1, b1v.y, acc[5]);
        acc[6] = fmaf(n1, b1v.z, acc[6]); acc[7] = fmaf(n1, b1v.w, acc[7]);
    }
    if (e < e1) {
        int2 p = er[e];
        const float* s0 = hp + (size_t)p.x * FDIM;
        float4 a0 = *(const float4*)s0, b0 = *(const float4*)(s0 + 4);
        float nv = __int_as_float(p.y);
        acc[0] = fmaf(nv, a0.x, acc[0]); acc[1] = fmaf(nv, a0.y, acc[1]);
        acc[2] = fmaf(nv, a0.z, acc[2]); acc[3] = fmaf(nv, a0.w, acc[3]);
        acc[4] = fmaf(nv, b0.x, acc[4]); acc[5] = fmaf(nv, b0.y, acc[5]);
        acc[6] = fmaf(nv, b0.z, acc[6]); acc[7] = fmaf(nv, b0.w, acc[7]);
    }
    {   // self-loop term
        float dv = dinv_g[c];
        float d2 = dv * dv;
        const float* s0 = hp + (size_t)c * FDIM;
        float4 a0 = *(const float4*)s0, b0 = *(const float4*)(s0 + 4);
        acc[0] = fmaf(d2, a0.x, acc[0]); acc[1] = fmaf(d2, a0.y, acc[1]);
        acc[2] = fmaf(d2, a0.z, acc[2]); acc[3] = fmaf(d2, a0.w, acc[3]);
        acc[4] = fmaf(d2, b0.x, acc[4]); acc[5] = fmaf(d2, b0.y, acc[5]);
        acc[6] = fmaf(d2, b0.z, acc[6]); acc[7] = fmaf(d2, b0.w, acc[7]);
    }
    *(uint4*)(outB + (size_t)c * FDIM + f) = f2bf8v(acc);
}

// ---------------------------------------------------------------------------
// XCD-feature-sliced aggregation, bf16 input, sequential accumulate,
// 4-edge unroll (round-13 proven). Natural node order (round 12: perm
// regresses). z = sA*acc (+d2*h[c] if dinv) (+sB*other[c]) (+bias); celu?
// ---------------------------------------------------------------------------
template<int SL>
__global__ __launch_bounds__(256) void k_sagg(
    const ushort_t* __restrict__ h, int hs, int hoff,
    const int2* __restrict__ er, const int* __restrict__ rp,
    const float* __restrict__ dinv_g,
    const ushort_t* __restrict__ other, int os, int ooff, float sB,
    const float* __restrict__ bias, float sA,
    ushort_t* __restrict__ outB, float* __restrict__ outF, int outs, int celu)
{
    const int id  = blockIdx.x;
    const int sl  = id % SL;
    const int tid = threadIdx.x;
    const int c   = (id / SL) * 32 + (tid >> 3);
    if (c >= N_NODES) return;
    const int f = sl * 64 + ((tid & 7) << 3);
    const ushort_t* hp = h + hoff + f;

    float acc[8] = {0.f, 0.f, 0.f, 0.f, 0.f, 0.f, 0.f, 0.f};
    int e = rp[c];
    const int e1 = rp[c + 1];
    for (; e + 4 <= e1; e += 4) {
        int2 p0 = er[e], p1 = er[e + 1], p2 = er[e + 2], p3 = er[e + 3];
        uint4 u0 = *(const uint4*)(hp + (size_t)p0.x * hs);
        uint4 u1 = *(const uint4*)(hp + (size_t)p1.x * hs);
        uint4 u2 = *(const uint4*)(hp + (size_t)p2.x * hs);
        uint4 u3 = *(const uint4*)(hp + (size_t)p3.x * hs);
        float n0 = __int_as_float(p0.y), n1 = __int_as_float(p1.y);
        float n2 = __int_as_float(p2.y), n3 = __int_as_float(p3.y);
        float v0[8], v1[8], v2[8], v3[8];
        bf2f8(u0, v0); bf2f8(u1, v1); bf2f8(u2, v2); bf2f8(u3, v3);
#pragma unroll
        for (int i = 0; i < 8; ++i) {
            acc[i] = fmaf(n0, v0[i], acc[i]);
            acc[i] = fmaf(n1, v1[i], acc[i]);
            acc[i] = fmaf(n2, v2[i], acc[i]);
            acc[i] = fmaf(n3, v3[i], acc[i]);
        }
    }
    for (; e < e1; ++e) {
        int2 p = er[e];
        uint4 u = *(const uint4*)(hp + (size_t)p.x * hs);
        float nv = __int_as_float(p.y);
        float v[8]; bf2f8(u, v);
#pragma unroll
        for (int i = 0; i < 8; ++i) acc[i] = fmaf(nv, v[i], acc[i]);
    }

    if (dinv_g) {                       // GCN self-loop term
        float dv = dinv_g[c];
        float d2 = dv * dv;
        uint4 u = *(const uint4*)(hp + (size_t)c * hs);
        float v[8]; bf2f8(u, v);
#pragma unroll
        for (int i = 0; i < 8; ++i) acc[i] = fmaf(d2, v[i], acc[i]);
    }
    float r[8];
#pragma unroll
    for (int i = 0; i < 8; ++i) r[i] = sA * acc[i];
    if (other) {
        uint4 u = *(const uint4*)(other + (size_t)c * os + ooff + f);
        float o[8]; bf2f8(u, o);
#pragma unroll
        for (int i = 0; i < 8; ++i) r[i] = fmaf(sB, o[i], r[i]);
    }
    if (bias) {
#pragma unroll
        for (int i = 0; i < 8; ++i) r[i] += bias[f + i];
    }
    if (celu) {
#pragma unroll
        for (int i = 0; i < 8; ++i) r[i] = r[i] > 0.f ? r[i] : expm1f(r[i]);
    }
    if (outF) {
        float* op = outF + (size_t)c * outs + f;
        *(float4*)op       = make_float4(r[0], r[1], r[2], r[3]);
        *(float4*)(op + 4) = make_float4(r[4], r[5], r[6], r[7]);
    } else {
        *(uint4*)(outB + (size_t)c * outs + f) = f2bf8v(r);
    }
}

// ---------------------------------------------------------------------------

extern "C" void kernel_launch(void* const* d_in, const int* in_sizes, int n_in,
                              void* d_out, int out_size, void* d_ws, size_t ws_size,
                              hipStream_t stream) {
    const float* x  = (const float*)d_in[0];
    const int*   ei = (const int*)d_in[1];
    const float* ew = (const float*)d_in[2];
    const float* W1 = (const float*)d_in[3];
    const float* b1 = (const float*)d_in[4];
    const float* W2 = (const float*)d_in[5];
    const float* b2 = (const float*)d_in[6];
    const float* Wc = (const float*)d_in[7];
    const float* bc = (const float*)d_in[8];
    float* out = (float*)d_out;

    const int* row = ei;
    const int* col = ei + N_EDGES;

    char* ws = (char*)d_ws;
    size_t off = 0;
    auto alloc = [&](size_t bytes) -> void* {
        void* p = ws + off;
        off += (bytes + 255) & ~(size_t)255;
        return p;
    };
    ushort_t* bufA  = (ushort_t*)alloc((size_t)N_NODES * FDIM * 2);   // Z / Z2
    ushort_t* bufB  = (ushort_t*)alloc((size_t)N_NODES * FDIM * 2);   // h1a / T0
    ushort_t* Y     = (ushort_t*)alloc((size_t)N_NODES * NCAT * 2);   // [Y0|Y1|Y2]
    ushort_t* P     = (ushort_t*)alloc((size_t)N_NODES * DOUT * 2);
    ushort_t* W1t   = (ushort_t*)alloc((size_t)FDIM * FDIM * 2);
    ushort_t* W2t   = (ushort_t*)alloc((size_t)FDIM * FDIM * 2);
    ushort_t* Wcatt = (ushort_t*)alloc((size_t)NCAT * FDIM * 2);
    size_t zs = off;
    float* deg_g  = (float*)alloc((size_t)N_NODES * 4);
    float* deg_c  = (float*)alloc((size_t)N_NODES * 4);
    int*   counts = (int*)alloc((size_t)N_NODES * 4);
    int*   fillb  = (int*)alloc((size_t)N_NODES * 4);
    size_t ze = off;
    float* dinv_g = (float*)alloc((size_t)N_NODES * 4);
    float* dinv_c = (float*)alloc((size_t)N_NODES * 4);
    int*   rp     = (int*)alloc((size_t)(N_NODES + 1) * 4);
    int*   part   = (int*)alloc(64 * 4);
    int2*  eg     = (int2*)alloc((size_t)N_EDGES * 8);
    int2*  ec     = (int2*)alloc((size_t)N_EDGES * 8);

    const int TB = 256;
    dim3 edgeGrid((N_EDGES + TB - 1) / TB);
    int nScanB = (N_NODES + 255) / 256;     // 40

    // ---- preprocessing ----
    hipMemsetAsync(ws + zs, 0, ze - zs, stream);
    k_pre1<<<EDGE_BLOCKS + 224, 256, 0, stream>>>(
        row, col, ew, deg_g, deg_c, counts, W1, W1t, W2, W2t, Wc, Wcatt);
    k_dinv_scan1<<<nScanB, 256, 0, stream>>>(deg_g, deg_c, dinv_g, dinv_c, counts, rp, part, N_NODES);
    k_scan23<<<nScanB, 256, 0, stream>>>(rp, part, nScanB, N_NODES);
    k_fill<<<edgeGrid, TB, 0, stream>>>(row, col, ew, dinv_g, dinv_c, rp, fillb, eg, ec, N_EDGES);

    auto mgemm = [&](const ushort_t* A, const ushort_t* Bt, int N,
                     const float* bias, ushort_t* oB) {
        int nbx = (N_NODES + 63) / 64, nby = N / 128;   // 157, {4,6}
        int G = 8 * (((nbx + 7) / 8) * nby);            // 640 / 960
        k_mgemm<<<G, 256, 0, stream>>>(A, FDIM, Bt, FDIM, N_NODES, FDIM, N, nbx, nby, bias, oB);
    };
    int g8 = ((N_NODES + 31) / 32) * 8;     // 313*8
    int g4 = ((N_NODES + 31) / 32) * 4;     // 313*4

    // ---- GCN layer 1 (commuted): Z = Âx (fp32 gather); h1a = celu(Z@W1+b1) ----
    k_saggF<<<g8, 256, 0, stream>>>(x, eg, rp, dinv_g, bufA);
    mgemm(bufA, W1t, FDIM, b1, bufB);
    // ---- GCN layer 2 (commuted): Z2 = Âh1a; T0 = celu(Z2@W2+b2) ----
    k_sagg<8><<<g8, 256, 0, stream>>>(bufB, FDIM, 0, eg, rp, dinv_g,
                                      (const ushort_t*)nullptr, 0, 0, 0.f,
                                      (const float*)nullptr, 1.f,
                                      bufA, (float*)nullptr, FDIM, 0);
    mgemm(bufA, W2t, FDIM, b2, bufB);
    // ---- Cheb (commuted): Y = T0 @ [W0-W2 | W1 | W2] ----
    mgemm(bufB, Wcatt, NCAT, (const float*)nullptr, Y);
    // P = Y1 + 2*Lhat(Y2)
    k_sagg<4><<<g4, 256, 0, stream>>>(Y, NCAT, 2 * DOUT, ec, rp,
                                      (const float*)nullptr,
                                      Y, NCAT, DOUT, 1.f,
                                      (const float*)nullptr, 2.f,
                                      P, (float*)nullptr, DOUT, 0);
    // out = celu(Y0 + Lhat(P) + bc)   (fp32 straight to d_out)
    k_sagg<4><<<g4, 256, 0, stream>>>(P, DOUT, 0, ec, rp,
                                      (const float*)nullptr,
                                      Y, NCAT, 0, 1.f,
                                      bc, 1.f,
                                      (ushort_t*)nullptr, out, DOUT, 1);
}

// Round 15
// 238.565 us; speedup vs baseline: 1.0690x; 1.0690x over previous
//
#include <hip/hip_runtime.h>
#include <math.h>

#define N_NODES 10000
#define N_EDGES 160000
#define FDIM    512
#define DOUT    256
#define NCAT    768     // [W0-W2 | W1 | W2]

typedef unsigned short ushort_t;
typedef unsigned int   uint_t;
typedef __attribute__((ext_vector_type(8))) short bf16x8;
typedef __attribute__((ext_vector_type(4))) float f32x4;

// ---------------------------------------------------------------------------
// helpers
// ---------------------------------------------------------------------------
__device__ inline ushort_t f2bf(float f) {
    uint_t u = __float_as_uint(f);
    u += 0x7fffu + ((u >> 16) & 1u);        // round-to-nearest-even
    return (ushort_t)(u >> 16);
}
__device__ inline void bf2f8(uint4 u, float* v) {
    v[0] = __uint_as_float(u.x << 16); v[1] = __uint_as_float(u.x & 0xffff0000u);
    v[2] = __uint_as_float(u.y << 16); v[3] = __uint_as_float(u.y & 0xffff0000u);
    v[4] = __uint_as_float(u.z << 16); v[5] = __uint_as_float(u.z & 0xffff0000u);
    v[6] = __uint_as_float(u.w << 16); v[7] = __uint_as_float(u.w & 0xffff0000u);
}
__device__ inline uint4 f2bf8v(const float* v) {
    uint4 u;
    u.x = (uint_t)f2bf(v[0]) | ((uint_t)f2bf(v[1]) << 16);
    u.y = (uint_t)f2bf(v[2]) | ((uint_t)f2bf(v[3]) << 16);
    u.z = (uint_t)f2bf(v[4]) | ((uint_t)f2bf(v[5]) << 16);
    u.w = (uint_t)f2bf(v[6]) | ((uint_t)f2bf(v[7]) << 16);
    return u;
}
__device__ inline void gld_lds16(const ushort_t* g, ushort_t* l) {
    __builtin_amdgcn_global_load_lds(
        (const __attribute__((address_space(1))) unsigned int*)g,
        (__attribute__((address_space(3))) unsigned int*)l,
        16, 0, 0);
}

// ---------------------------------------------------------------------------
// Merged preprocessing stage 1 + conversions.
// Blocks [0,EDGE_BLOCKS): edge degrees/counts (atomics).
// Blocks [EDGE_BLOCKS, +5000): x -> bf16 (4 floats/thread, vectorized).
// Then 64 tiles W1^T, 64 tiles W2^T, 96 tiles Wcat^T where
// Wcat = [W0-W2 | W1 | W2] (512x768), stored transposed [768][512].
// ---------------------------------------------------------------------------
#define EDGE_BLOCKS 625   // 160000 / 256
#define XB_BLOCKS   5000  // 10000*512 / 4 / 256

__global__ __launch_bounds__(256) void k_pre1(
    const int* __restrict__ row, const int* __restrict__ col,
    const float* __restrict__ w,
    float* deg_g, float* deg_c, int* counts,
    const float* __restrict__ x,  ushort_t* __restrict__ xb,
    const float* __restrict__ W1, ushort_t* __restrict__ W1t,
    const float* __restrict__ W2, ushort_t* __restrict__ W2t,
    const float* __restrict__ Wc, ushort_t* __restrict__ Wcatt)
{
    __shared__ float tile[64][65];
    int b = blockIdx.x;
    int tid = threadIdx.x;
    if (b < EDGE_BLOCKS) {
        int e = b * 256 + tid;
        if (e < N_EDGES) {
            int r = row[e], c = col[e];
            float wv = w[e];
            atomicAdd(&deg_g[c], wv);
            if (r != c) atomicAdd(&deg_c[r], wv);
            atomicAdd(&counts[c], 1);
        }
        return;
    }
    b -= EDGE_BLOCKS;
    if (b < XB_BLOCKS) {
        int t = b * 256 + tid;
        float4 v = *(const float4*)(x + (size_t)t * 4);
        uint2 p;
        p.x = (uint_t)f2bf(v.x) | ((uint_t)f2bf(v.y) << 16);
        p.y = (uint_t)f2bf(v.z) | ((uint_t)f2bf(v.w) << 16);
        *(uint2*)(xb + (size_t)t * 4) = p;
        return;
    }
    b -= XB_BLOCKS;
    const float* src; const float* src2 = nullptr;
    ushort_t* dst; int kt, ntG, srcld;
    if (b < 64) {                       // W1 [512][512]
        kt = b >> 3; ntG = b & 7; srcld = FDIM;
        src = W1 + (size_t)(kt * 64) * FDIM + ntG * 64;
        dst = W1t;
    } else if (b < 128) {               // W2
        int bb = b - 64;
        kt = bb >> 3; ntG = bb & 7; srcld = FDIM;
        src = W2 + (size_t)(kt * 64) * FDIM + ntG * 64;
        dst = W2t;
    } else {                            // Wcat: ntG in [0,12), kt in [0,8)
        int bb = b - 128;
        ntG = bb / 8; kt = bb % 8; srcld = DOUT;
        int s = ntG >> 2;               // section 0,1,2
        int nl = (ntG & 3) * 64;        // col within 256
        if (s == 0) {                   // W0 - W2
            src  = Wc + (size_t)(kt * 64) * DOUT + nl;
            src2 = Wc + (size_t)2 * FDIM * DOUT + (size_t)(kt * 64) * DOUT + nl;
        } else if (s == 1) {            // W1 (Cheb k=1)
            src  = Wc + (size_t)1 * FDIM * DOUT + (size_t)(kt * 64) * DOUT + nl;
        } else {                        // W2
            src  = Wc + (size_t)2 * FDIM * DOUT + (size_t)(kt * 64) * DOUT + nl;
        }
        dst = Wcatt;
    }
    // load phase: thread (r = tid>>2, c0 = (tid&3)*16) loads 16 floats
    {
        int r = tid >> 2, c0 = (tid & 3) * 16;
        const float* sp = src + (size_t)r * srcld + c0;
#pragma unroll
        for (int q = 0; q < 4; ++q) {
            float4 a = *(const float4*)(sp + q * 4);
            if (src2) {
                float4 bsub = *(const float4*)(src2 + (size_t)r * srcld + c0 + q * 4);
                a.x -= bsub.x; a.y -= bsub.y; a.z -= bsub.z; a.w -= bsub.w;
            }
            tile[r][c0 + q * 4 + 0] = a.x;
            tile[r][c0 + q * 4 + 1] = a.y;
            tile[r][c0 + q * 4 + 2] = a.z;
            tile[r][c0 + q * 4 + 3] = a.w;
        }
    }
    __syncthreads();
    // store phase: thread (n = tid>>2, k0 = (tid&3)*16) writes 16 bf16 (32 B)
    {
        int n = tid >> 2, k0 = (tid & 3) * 16;
        float v[16];
#pragma unroll
        for (int i = 0; i < 16; ++i) v[i] = tile[k0 + i][n];
        uint4 u0 = f2bf8v(v);
        uint4 u1 = f2bf8v(v + 8);
        ushort_t* dp = dst + (size_t)(ntG * 64 + n) * FDIM + kt * 64 + k0;
        *(uint4*)dp = u0;
        *(uint4*)(dp + 8) = u1;
    }
}

__global__ __launch_bounds__(256) void k_dinv_scan1(
    const float* __restrict__ deg_g, const float* __restrict__ deg_c,
    float* __restrict__ dinv_g, float* __restrict__ dinv_c,
    const int* __restrict__ counts, int* __restrict__ rp,
    int* __restrict__ part, int n)
{
    __shared__ int s[256];
    int tid = threadIdx.x;
    int i = blockIdx.x * 256 + tid;
    if (i < n) {
        dinv_g[i] = rsqrtf(deg_g[i] + 1.0f);
        float d = deg_c[i];
        dinv_c[i] = d > 0.f ? rsqrtf(d) : 0.f;
    }
    int v = (i < n) ? counts[i] : 0;
    s[tid] = v;
    __syncthreads();
    for (int o = 1; o < 256; o <<= 1) {
        int t = (tid >= o) ? s[tid - o] : 0;
        __syncthreads();
        s[tid] += t;
        __syncthreads();
    }
    if (i < n) rp[i] = s[tid] - v;
    if (tid == 255) part[blockIdx.x] = s[255];
}

// fused scan2+scan3: every block redundantly wave-scans the <=64 partials
__global__ __launch_bounds__(256) void k_scan23(int* __restrict__ rp,
                                                const int* __restrict__ part,
                                                int nb, int n) {
    __shared__ int soff[64];
    __shared__ int stot;
    int tid = threadIdx.x;
    if (tid < 64) {
        int v = (tid < nb) ? part[tid] : 0;
        int x = v;
        for (int o = 1; o < 64; o <<= 1) {
            int y = __shfl_up(x, o, 64);
            if (tid >= o) x += y;
        }
        soff[tid] = x - v;
        if (tid == 63) stot = x;
    }
    __syncthreads();
    int i = blockIdx.x * 256 + tid;
    if (i < n) rp[i] += soff[blockIdx.x];
    if (blockIdx.x == 0 && tid == 0) rp[n] = stot;
}

// edge records (src, norm) 8B; n_c stored NEGATED so lhat is a plain sum
__global__ void k_fill(const int* __restrict__ row, const int* __restrict__ col,
                       const float* __restrict__ w,
                       const float* __restrict__ dinv_g, const float* __restrict__ dinv_c,
                       const int* __restrict__ rp, int* __restrict__ fill,
                       int2* __restrict__ eg, int2* __restrict__ ec, int E) {
    int e = blockIdx.x * blockDim.x + threadIdx.x;
    if (e >= E) return;
    int r = row[e], c = col[e];
    float wv = w[e];
    float ng = dinv_g[r] * wv * dinv_g[c];
    float w0 = (r == c) ? 0.f : wv;
    float nc = -(dinv_c[r] * w0 * dinv_c[c]);
    int pos = rp[c] + atomicAdd(&fill[c], 1);
    eg[pos] = make_int2(r, __float_as_int(ng));
    ec[pos] = make_int2(r, __float_as_int(nc));
}

// ---------------------------------------------------------------------------
// Staged bf16 MFMA GEMM (m97 structure). 64x128 tile, BK=32, 256 thr =
// 4 waves 2x2; wave tile 32x64 -> 2x4 MFMA 16x16x32. 12 KB LDS.
// 640-960 blocks -> 2.5-3.7 blocks/CU. XCD swizzle: j=id&7 -> XCD;
// bx=(t/nby)*8+j so one XCD owns a contiguous 1/8 slice of A rows.
// ---------------------------------------------------------------------------
__global__ __launch_bounds__(256) void k_mgemm(
    const ushort_t* __restrict__ A, int lda,
    const ushort_t* __restrict__ Bt, int ldb,
    int M, int K, int N, int nbx, int nby,
    ushort_t* __restrict__ outB)
{
    __shared__ ushort_t As[64 * 32];
    __shared__ ushort_t Bs[128 * 32];

    int id = blockIdx.x;
    int j = id & 7, t = id >> 3;
    int by = t % nby;
    int bx = (t / nby) * 8 + j;
    if (bx >= nbx) return;

    const int tid  = threadIdx.x;
    const int w    = tid >> 6;
    const int lane = tid & 63;
    const int l15  = lane & 15;
    const int quad = lane >> 4;
    const int bm = bx * 64, bn = by * 128;
    const int wm = (w & 1) * 32;
    const int wn = (w >> 1) * 64;

    const int sr = lane >> 2;           // 0..15
    const int sc = (lane & 3) * 8;      // 0,8,16,24
    // A: wave w stages rows w*16 .. +15 (1 inst)
    int arow = min(bm + w * 16 + sr, M - 1);
    const ushort_t* ag = A + (size_t)arow * lda + sc;
    ushort_t* al = As + (w * 16 + sr) * 32 + sc;
    // B: wave w stages rows w*32 .. +31 (2 insts)
    const ushort_t* bg0 = Bt + (size_t)(bn + w * 32 + sr) * ldb + sc;
    const ushort_t* bg1 = bg0 + (size_t)16 * ldb;
    ushort_t* bl0 = Bs + (w * 32 + sr) * 32 + sc;
    ushort_t* bl1 = bl0 + 16 * 32;

    f32x4 acc[2][4] = {};

    for (int k0 = 0; k0 < K; k0 += 32) {
        __syncthreads();
        gld_lds16(ag + k0, al);
        gld_lds16(bg0 + k0, bl0);
        gld_lds16(bg1 + k0, bl1);
        __syncthreads();
        bf16x8 af[2], bfr[4];
#pragma unroll
        for (int i = 0; i < 2; ++i)
            af[i] = *(const bf16x8*)(As + (wm + i * 16 + l15) * 32 + quad * 8);
#pragma unroll
        for (int jj = 0; jj < 4; ++jj)
            bfr[jj] = *(const bf16x8*)(Bs + (wn + jj * 16 + l15) * 32 + quad * 8);
#pragma unroll
        for (int i = 0; i < 2; ++i)
#pragma unroll
            for (int jj = 0; jj < 4; ++jj)
                acc[i][jj] = __builtin_amdgcn_mfma_f32_16x16x32_bf16(af[i], bfr[jj], acc[i][jj], 0, 0, 0);
    }

    // C/D layout: col = lane&15, row = quad*4 + reg (m89-verified)
#pragma unroll
    for (int i = 0; i < 2; ++i) {
        int rowb = bm + wm + i * 16 + quad * 4;
#pragma unroll
        for (int jj = 0; jj < 4; ++jj) {
            int col = bn + wn + jj * 16 + l15;
#pragma unroll
            for (int r = 0; r < 4; ++r) {
                int rr = rowb + r;
                if (rr < M)
                    outB[(size_t)rr * N + col] = f2bf(acc[i][jj][r]);
            }
        }
    }
}

// ---------------------------------------------------------------------------
// XCD-feature-sliced aggregation, sequential accumulate, 4-edge unroll.
// SL slices of 64 features (width = SL*64). Block 256 thr = 32 consecutive
// nodes x 8 lanes (natural order -> coalesced out-rows, sequential CSR reads;
// round 12 showed degree-sorted perm REGRESSES by breaking this locality).
// Grid = ceil(N/32)*SL with slice = id%SL (round-robin -> per-XCD slice
// locality; per-XCD gather set = width*2B*10000/SL = 1.28 MB -> L2).
// z = sA*acc (+d2*h[c] if dinv) (+sB*other[c]) (+bias); out = celu?(z)
// ---------------------------------------------------------------------------
template<int SL>
__global__ __launch_bounds__(256) void k_sagg(
    const ushort_t* __restrict__ h, int hs, int hoff,
    const int2* __restrict__ er, const int* __restrict__ rp,
    const float* __restrict__ dinv_g,
    const ushort_t* __restrict__ other, int os, int ooff, float sB,
    const float* __restrict__ bias, float sA,
    ushort_t* __restrict__ outB, float* __restrict__ outF, int outs, int celu)
{
    const int id  = blockIdx.x;
    const int sl  = id % SL;
    const int tid = threadIdx.x;
    const int c   = (id / SL) * 32 + (tid >> 3);
    if (c >= N_NODES) return;
    const int f = sl * 64 + ((tid & 7) << 3);
    const ushort_t* hp = h + hoff + f;

    float acc[8] = {0.f, 0.f, 0.f, 0.f, 0.f, 0.f, 0.f, 0.f};
    int e = rp[c];
    const int e1 = rp[c + 1];
    for (; e + 4 <= e1; e += 4) {
        int2 p0 = er[e], p1 = er[e + 1], p2 = er[e + 2], p3 = er[e + 3];
        uint4 u0 = *(const uint4*)(hp + (size_t)p0.x * hs);
        uint4 u1 = *(const uint4*)(hp + (size_t)p1.x * hs);
        uint4 u2 = *(const uint4*)(hp + (size_t)p2.x * hs);
        uint4 u3 = *(const uint4*)(hp + (size_t)p3.x * hs);
        float n0 = __int_as_float(p0.y), n1 = __int_as_float(p1.y);
        float n2 = __int_as_float(p2.y), n3 = __int_as_float(p3.y);
        float v0[8], v1[8], v2[8], v3[8];
        bf2f8(u0, v0); bf2f8(u1, v1); bf2f8(u2, v2); bf2f8(u3, v3);
#pragma unroll
        for (int i = 0; i < 8; ++i) {
            acc[i] = fmaf(n0, v0[i], acc[i]);
            acc[i] = fmaf(n1, v1[i], acc[i]);
            acc[i] = fmaf(n2, v2[i], acc[i]);
            acc[i] = fmaf(n3, v3[i], acc[i]);
        }
    }
    for (; e < e1; ++e) {
        int2 p = er[e];
        uint4 u = *(const uint4*)(hp + (size_t)p.x * hs);
        float nv = __int_as_float(p.y);
        float v[8]; bf2f8(u, v);
#pragma unroll
        for (int i = 0; i < 8; ++i) acc[i] = fmaf(nv, v[i], acc[i]);
    }

    if (dinv_g) {                       // GCN self-loop term
        float dv = dinv_g[c];
        float d2 = dv * dv;
        uint4 u = *(const uint4*)(hp + (size_t)c * hs);
        float v[8]; bf2f8(u, v);
#pragma unroll
        for (int i = 0; i < 8; ++i) acc[i] = fmaf(d2, v[i], acc[i]);
    }
    float r[8];
#pragma unroll
    for (int i = 0; i < 8; ++i) r[i] = sA * acc[i];
    if (other) {
        uint4 u = *(const uint4*)(other + (size_t)c * os + ooff + f);
        float o[8]; bf2f8(u, o);
#pragma unroll
        for (int i = 0; i < 8; ++i) r[i] = fmaf(sB, o[i], r[i]);
    }
    if (bias) {
#pragma unroll
        for (int i = 0; i < 8; ++i) r[i] += bias[f + i];
    }
    if (celu) {
#pragma unroll
        for (int i = 0; i < 8; ++i) r[i] = r[i] > 0.f ? r[i] : expm1f(r[i]);
    }
    if (outF) {
        float* op = outF + (size_t)c * outs + f;
        *(float4*)op       = make_float4(r[0], r[1], r[2], r[3]);
        *(float4*)(op + 4) = make_float4(r[4], r[5], r[6], r[7]);
    } else {
        *(uint4*)(outB + (size_t)c * outs + f) = f2bf8v(r);
    }
}

// ---------------------------------------------------------------------------

extern "C" void kernel_launch(void* const* d_in, const int* in_sizes, int n_in,
                              void* d_out, int out_size, void* d_ws, size_t ws_size,
                              hipStream_t stream) {
    const float* x  = (const float*)d_in[0];
    const int*   ei = (const int*)d_in[1];
    const float* ew = (const float*)d_in[2];
    const float* W1 = (const float*)d_in[3];
    const float* b1 = (const float*)d_in[4];
    const float* W2 = (const float*)d_in[5];
    const float* b2 = (const float*)d_in[6];
    const float* Wc = (const float*)d_in[7];
    const float* bc = (const float*)d_in[8];
    float* out = (float*)d_out;

    const int* row = ei;
    const int* col = ei + N_EDGES;

    char* ws = (char*)d_ws;
    size_t off = 0;
    auto alloc = [&](size_t bytes) -> void* {
        void* p = ws + off;
        off += (bytes + 255) & ~(size_t)255;
        return p;
    };
    ushort_t* xb    = (ushort_t*)alloc((size_t)N_NODES * FDIM * 2);
    ushort_t* bufA  = (ushort_t*)alloc((size_t)N_NODES * FDIM * 2);   // h1 / h2
    ushort_t* bufB  = (ushort_t*)alloc((size_t)N_NODES * FDIM * 2);   // h1a / T0
    ushort_t* Y     = (ushort_t*)alloc((size_t)N_NODES * NCAT * 2);   // [Y0|Y1|Y2]
    ushort_t* P     = (ushort_t*)alloc((size_t)N_NODES * DOUT * 2);
    ushort_t* W1t   = (ushort_t*)alloc((size_t)FDIM * FDIM * 2);
    ushort_t* W2t   = (ushort_t*)alloc((size_t)FDIM * FDIM * 2);
    ushort_t* Wcatt = (ushort_t*)alloc((size_t)NCAT * FDIM * 2);
    size_t zs = off;
    float* deg_g  = (float*)alloc((size_t)N_NODES * 4);
    float* deg_c  = (float*)alloc((size_t)N_NODES * 4);
    int*   counts = (int*)alloc((size_t)N_NODES * 4);
    int*   fillb  = (int*)alloc((size_t)N_NODES * 4);
    size_t ze = off;
    float* dinv_g = (float*)alloc((size_t)N_NODES * 4);
    float* dinv_c = (float*)alloc((size_t)N_NODES * 4);
    int*   rp     = (int*)alloc((size_t)(N_NODES + 1) * 4);
    int*   part   = (int*)alloc(64 * 4);
    int2*  eg     = (int2*)alloc((size_t)N_EDGES * 8);
    int2*  ec     = (int2*)alloc((size_t)N_EDGES * 8);

    const int TB = 256;
    dim3 edgeGrid((N_EDGES + TB - 1) / TB);
    int nScanB = (N_NODES + 255) / 256;     // 40

    // ---- preprocessing + conversions ----
    hipMemsetAsync(ws + zs, 0, ze - zs, stream);
    k_pre1<<<EDGE_BLOCKS + XB_BLOCKS + 224, 256, 0, stream>>>(
        row, col, ew, deg_g, deg_c, counts,
        x, xb, W1, W1t, W2, W2t, Wc, Wcatt);
    k_dinv_scan1<<<nScanB, 256, 0, stream>>>(deg_g, deg_c, dinv_g, dinv_c, counts, rp, part, N_NODES);
    k_scan23<<<nScanB, 256, 0, stream>>>(rp, part, nScanB, N_NODES);
    k_fill<<<edgeGrid, TB, 0, stream>>>(row, col, ew, dinv_g, dinv_c, rp, fillb, eg, ec, N_EDGES);

    auto mgemm = [&](const ushort_t* A, const ushort_t* Bt, int N, ushort_t* oB) {
        int nbx = (N_NODES + 63) / 64, nby = N / 128;   // 157, {4,6}
        int G = 8 * (((nbx + 7) / 8) * nby);            // 640 / 960
        k_mgemm<<<G, 256, 0, stream>>>(A, FDIM, Bt, FDIM, N_NODES, FDIM, N, nbx, nby, oB);
    };
    int g8 = ((N_NODES + 31) / 32) * 8;     // 313*8
    int g4 = ((N_NODES + 31) / 32) * 4;     // 313*4

    // ---- GCN layer 1: h1 = x@W1; h1a = celu(agg(h1)+b1) ----
    mgemm(xb, W1t, FDIM, bufA);
    k_sagg<8><<<g8, 256, 0, stream>>>(bufA, FDIM, 0, eg, rp, dinv_g,
                                      (const ushort_t*)nullptr, 0, 0, 0.f,
                                      b1, 1.f, bufB, (float*)nullptr, FDIM, 1);
    // ---- GCN layer 2 ----
    mgemm(bufB, W2t, FDIM, bufA);
    k_sagg<8><<<g8, 256, 0, stream>>>(bufA, FDIM, 0, eg, rp, dinv_g,
                                      (const ushort_t*)nullptr, 0, 0, 0.f,
                                      b2, 1.f, bufB, (float*)nullptr, FDIM, 1);
    // ---- Cheb (commuted): Y = T0 @ [W0-W2 | W1 | W2] ----
    mgemm(bufB, Wcatt, NCAT, Y);
    // P = Y1 + 2*Lhat(Y2)
    k_sagg<4><<<g4, 256, 0, stream>>>(Y, NCAT, 2 * DOUT, ec, rp,
                                      (const float*)nullptr,
                                      Y, NCAT, DOUT, 1.f,
                                      (const float*)nullptr, 2.f,
                                      P, (float*)nullptr, DOUT, 0);
    // out = celu(Y0 + Lhat(P) + bc)   (fp32 straight to d_out)
    k_sagg<4><<<g4, 256, 0, stream>>>(P, DOUT, 0, ec, rp,
                                      (const float*)nullptr,
                                      Y, NCAT, 0, 1.f,
                                      bc, 1.f,
                                      (ushort_t*)nullptr, out, DOUT, 1);
}